// Round 1
// baseline (264.001 us; speedup 1.0000x reference)
//
#include <hip/hip_runtime.h>
#include <math.h>

// Problem constants (from reference):
// BS=32, N_IND=8 -> B=256 problems; N_STEP=100, ORDER=2, N_ORD=3.
// AtA is block-tridiagonal with 3x3 blocks; solve via block Cholesky.
#define NPROB 256
#define NSTEP 100
#define T1    99   // N_STEP-1

__global__ __launch_bounds__(64) void ode_block_tridiag_kernel(
    const float* __restrict__ coeffs,  // [256][100][3]
    const float* __restrict__ rhs,     // [256][100]
    const float* __restrict__ iv_rhs,  // [256][2]
    const float* __restrict__ steps,   // [256][99]
    float* __restrict__ out)           // u0[25600] u1[25600] u2[25600] eps[256] st[25344]
{
    const int b = blockIdx.x * blockDim.x + threadIdx.x;
    if (b >= NPROB) return;

    // Per-thread factor storage (scratch/private memory): 100*(6+9+3)*8B = 14.4KB
    double Lf[NSTEP][6];   // L_t lower: l00,l10,l11,l20,l21,l22
    double Mf[NSTEP][9];   // M_t row-major (valid for t>=1)
    double yf[NSTEP][3];   // forward-substituted rhs

    const float* cb = coeffs + b * NSTEP * 3;
    const float* rb = rhs    + b * NSTEP;
    const float* sb = steps  + b * T1;

    double yp0 = 0.0, yp1 = 0.0, yp2 = 0.0;  // y_{t-1}

    // ---------- forward sweep: build blocks on the fly, block-Cholesky ----------
    for (int t = 0; t < NSTEP; ++t) {
        const double c0 = (double)cb[t * 3 + 0];
        const double c1 = (double)cb[t * 3 + 1];
        const double c2 = (double)cb[t * 3 + 2];
        const double r  = (double)rb[t];

        // Eq-row contribution: c c^T and c*rhs
        double a00 = c0 * c0, a01 = c0 * c1, a02 = c0 * c2;
        double a11 = c1 * c1, a12 = c1 * c2, a22 = c2 * c2;
        double b0 = c0 * r, b1 = c1 * r, b2 = c2 * r;

        if (t == 0) {  // initial-value rows hit (0,0) and (1,1) of block 0
            a00 += 1.0; a11 += 1.0;
            b0 += (double)iv_rhs[b * 2 + 0];
            b1 += (double)iv_rhs[b * 2 + 1];
        }
        if (t < T1) {  // U(h_t): D-block t, "u" side
            const double h = (double)sb[t], h2 = h * h;
            a00 += 2.0;
            a01 += h;
            a02 += 0.5 * h2;
            a11 += h2 + 3.0;
            a12 += 0.5 * h2 * h + 1.5 * h;
            a22 += 0.25 * h2 * h2 + 1.25 * h2;
        }
        if (t > 0) {   // V(h_{t-1}): D-block t-1, "v" side; and coupling E(h_{t-1})
            const double hm = (double)sb[t - 1], hm2 = hm * hm;
            a00 += 2.0;
            a01 -= hm;
            a02 += 0.5 * hm2;
            a11 += hm2 + 3.0;
            a12 -= 0.5 * hm2 * hm + 1.5 * hm;
            a22 += 0.25 * hm2 * hm2 + 1.25 * hm2;

            // E(hm), row-major (block (t, t-1) of AtA)
            const double e00 = -2.0,       e01 = -hm,       e02 = -0.5 * hm2;
            const double e10 =  hm,        e11 = -3.0,      e12 = -1.5 * hm;
            const double e20 = -0.5 * hm2, e21 =  1.5 * hm, e22 =  0.25 * hm2;

            const double* Lp = Lf[t - 1];
            const double l00 = Lp[0], l10 = Lp[1], l11 = Lp[2];
            const double l20 = Lp[3], l21 = Lp[4], l22 = Lp[5];
            const double i0 = 1.0 / l00, i1 = 1.0 / l11, i2 = 1.0 / l22;

            // M_t = E * L_{t-1}^{-T}: per row, forward-solve L m^T = e^T
            const double m00 = e00 * i0;
            const double m01 = (e01 - l10 * m00) * i1;
            const double m02 = (e02 - l20 * m00 - l21 * m01) * i2;
            const double m10 = e10 * i0;
            const double m11 = (e11 - l10 * m10) * i1;
            const double m12 = (e12 - l20 * m10 - l21 * m11) * i2;
            const double m20 = e20 * i0;
            const double m21 = (e21 - l10 * m20) * i1;
            const double m22 = (e22 - l20 * m20 - l21 * m21) * i2;

            // Schur update: A_t -= M M^T
            a00 -= m00 * m00 + m01 * m01 + m02 * m02;
            a01 -= m00 * m10 + m01 * m11 + m02 * m12;
            a02 -= m00 * m20 + m01 * m21 + m02 * m22;
            a11 -= m10 * m10 + m11 * m11 + m12 * m12;
            a12 -= m10 * m20 + m11 * m21 + m12 * m22;
            a22 -= m20 * m20 + m21 * m21 + m22 * m22;

            // rhs update: b_t -= M y_{t-1}
            b0 -= m00 * yp0 + m01 * yp1 + m02 * yp2;
            b1 -= m10 * yp0 + m11 * yp1 + m12 * yp2;
            b2 -= m20 * yp0 + m21 * yp1 + m22 * yp2;

            double* Mp = Mf[t];
            Mp[0] = m00; Mp[1] = m01; Mp[2] = m02;
            Mp[3] = m10; Mp[4] = m11; Mp[5] = m12;
            Mp[6] = m20; Mp[7] = m21; Mp[8] = m22;
        }

        // 3x3 Cholesky of the (Schur-updated) diagonal block
        const double l00 = sqrt(a00);
        const double r0  = 1.0 / l00;
        const double l10 = a01 * r0;
        const double l20 = a02 * r0;
        const double l11 = sqrt(a11 - l10 * l10);
        const double r1  = 1.0 / l11;
        const double l21 = (a12 - l20 * l10) * r1;
        const double l22 = sqrt(a22 - l20 * l20 - l21 * l21);
        const double r2  = 1.0 / l22;

        // forward substitution: y_t = L^{-1} b
        const double y0 = b0 * r0;
        const double y1 = (b1 - l10 * y0) * r1;
        const double y2 = (b2 - l20 * y0 - l21 * y1) * r2;

        double* Lp = Lf[t];
        Lp[0] = l00; Lp[1] = l10; Lp[2] = l11; Lp[3] = l20; Lp[4] = l21; Lp[5] = l22;
        double* yq = yf[t];
        yq[0] = y0; yq[1] = y1; yq[2] = y2;
        yp0 = y0; yp1 = y1; yp2 = y2;
    }

    // ---------- backward sweep: L^T x = y ----------
    double x0 = 0.0, x1 = 0.0, x2 = 0.0;  // x_{t+1}
    for (int t = NSTEP - 1; t >= 0; --t) {
        double v0 = yf[t][0], v1 = yf[t][1], v2 = yf[t][2];
        if (t < NSTEP - 1) {
            const double* Mp = Mf[t + 1];
            // v -= M_{t+1}^T x_{t+1}
            v0 -= Mp[0] * x0 + Mp[3] * x1 + Mp[6] * x2;
            v1 -= Mp[1] * x0 + Mp[4] * x1 + Mp[7] * x2;
            v2 -= Mp[2] * x0 + Mp[5] * x1 + Mp[8] * x2;
        }
        const double* Lp = Lf[t];
        const double nx2 = v2 / Lp[5];
        const double nx1 = (v1 - Lp[4] * nx2) / Lp[2];
        const double nx0 = (v0 - Lp[1] * nx1 - Lp[3] * nx2) / Lp[0];
        x0 = nx0; x1 = nx1; x2 = nx2;

        out[            b * NSTEP + t] = (float)x0;  // u0
        out[25600 +     b * NSTEP + t] = (float)x1;  // u1
        out[51200 +     b * NSTEP + t] = (float)x2;  // u2
    }

    // eps (zeros) and st (copy of steps) — d_out is poisoned, must write them
    out[76800 + b] = 0.0f;
    for (int t = 0; t < T1; ++t)
        out[77056 + b * T1 + t] = sb[t];
}

extern "C" void kernel_launch(void* const* d_in, const int* in_sizes, int n_in,
                              void* d_out, int out_size, void* d_ws, size_t ws_size,
                              hipStream_t stream) {
    const float* coeffs = (const float*)d_in[0];  // 76800
    const float* rhs    = (const float*)d_in[1];  // 25600
    const float* iv_rhs = (const float*)d_in[2];  // 512
    const float* steps  = (const float*)d_in[3];  // 25344
    float* out = (float*)d_out;                   // 102400

    ode_block_tridiag_kernel<<<dim3(NPROB / 64), dim3(64), 0, stream>>>(
        coeffs, rhs, iv_rhs, steps, out);
}

// Round 2
// 70.559 us; speedup vs baseline: 3.7416x; 3.7416x over previous
//
#include <hip/hip_runtime.h>
#include <math.h>

// BS=32, N_IND=8 -> 256 independent problems; N_STEP=100, ORDER=2 (3x3 blocks).
// Normal-equations matrix AtA is block-tridiagonal (verified round 1, absmax 0.0).
// This version: block CYCLIC REDUCTION, one problem per workgroup, all state in
// LDS. Sequential depth ~14 levels instead of ~200 block-Cholesky steps.
#define NPROB 256
#define NSTEP 100
#define T1    99

__global__ __launch_bounds__(128) void ode_cr_kernel(
    const float* __restrict__ coeffs,  // [256][100][3]
    const float* __restrict__ rhs,     // [256][100]
    const float* __restrict__ iv_rhs,  // [256][2]
    const float* __restrict__ steps,   // [256][99]
    float* __restrict__ out)           // u0[25600] u1[25600] u2[25600] eps[256] st[25344]
{
    const int b   = blockIdx.x;
    const int tid = threadIdx.x;

    // Block-tridiagonal system state (indexed by original time-slot t):
    __shared__ double A[NSTEP][6];   // diag block, sym: a00,a01,a02,a11,a12,a22
    __shared__ double C[NSTEP][9];   // sub-diag block row t -> col t-1, row-major (t>=1)
    __shared__ double bb[NSTEP][3];  // rhs
    __shared__ double P[NSTEP][9];   // eliminated block: A^-1 * C        (row-major)
    __shared__ double Q[NSTEP][9];   // eliminated block: A^-1 * C_right^T
    __shared__ double z[NSTEP][3];   // eliminated block: A^-1 * b
    __shared__ double X[NSTEP][3];   // solution

    const float* cb = coeffs + b * NSTEP * 3;
    const float* rb = rhs    + b * NSTEP;
    const float* sb = steps  + b * T1;

    // ---------------- build blocks (parallel over t) ----------------
    if (tid < NSTEP) {
        const int t = tid;
        const double c0 = (double)cb[t * 3 + 0];
        const double c1 = (double)cb[t * 3 + 1];
        const double c2 = (double)cb[t * 3 + 2];
        const double r  = (double)rb[t];

        double a00 = c0 * c0, a01 = c0 * c1, a02 = c0 * c2;
        double a11 = c1 * c1, a12 = c1 * c2, a22 = c2 * c2;
        double b0 = c0 * r, b1 = c1 * r, b2 = c2 * r;

        if (t == 0) {
            a00 += 1.0; a11 += 1.0;
            b0 += (double)iv_rhs[b * 2 + 0];
            b1 += (double)iv_rhs[b * 2 + 1];
        }
        if (t < T1) {  // U(h_t)
            const double h = (double)sb[t], h2 = h * h;
            a00 += 2.0;
            a01 += h;
            a02 += 0.5 * h2;
            a11 += h2 + 3.0;
            a12 += 0.5 * h2 * h + 1.5 * h;
            a22 += 0.25 * h2 * h2 + 1.25 * h2;
        }
        if (t > 0) {   // V(h_{t-1}) and coupling E(h_{t-1})
            const double hm = (double)sb[t - 1], hm2 = hm * hm;
            a00 += 2.0;
            a01 -= hm;
            a02 += 0.5 * hm2;
            a11 += hm2 + 3.0;
            a12 -= 0.5 * hm2 * hm + 1.5 * hm;
            a22 += 0.25 * hm2 * hm2 + 1.25 * hm2;

            C[t][0] = -2.0;       C[t][1] = -hm;       C[t][2] = -0.5 * hm2;
            C[t][3] =  hm;        C[t][4] = -3.0;      C[t][5] = -1.5 * hm;
            C[t][6] = -0.5 * hm2; C[t][7] =  1.5 * hm; C[t][8] =  0.25 * hm2;
        }
        A[t][0] = a00; A[t][1] = a01; A[t][2] = a02;
        A[t][3] = a11; A[t][4] = a12; A[t][5] = a22;
        bb[t][0] = b0; bb[t][1] = b1; bb[t][2] = b2;
    }
    __syncthreads();

    // ---------------- cyclic reduction: 100->50->25->13->7->4->2->1 ----------------
    int ncount[8];
    int n = NSTEP, stride = 1, nlev = 0;
    while (n > 1) {
        ncount[nlev] = n;

        // odd phase: factor eliminated blocks, compute P,Q,z
        int j = 2 * tid + 1;
        if (j < n) {
            const int t = j * stride;
            const double a00 = A[t][0], a01 = A[t][1], a02 = A[t][2];
            const double a11 = A[t][3], a12 = A[t][4], a22 = A[t][5];
            const double l00 = sqrt(a00), i0 = 1.0 / l00;
            const double l10 = a01 * i0, l20 = a02 * i0;
            const double l11 = sqrt(a11 - l10 * l10), i1 = 1.0 / l11;
            const double l21 = (a12 - l20 * l10) * i1;
            const double l22 = sqrt(a22 - l20 * l20 - l21 * l21), i2 = 1.0 / l22;

#define SOLVE3(in0, in1, in2, o0, o1, o2)                                   \
            {                                                               \
                const double f0 = (in0) * i0;                               \
                const double f1 = ((in1) - l10 * f0) * i1;                  \
                const double f2 = ((in2) - l20 * f0 - l21 * f1) * i2;       \
                o2 = f2 * i2;                                               \
                o1 = (f1 - l21 * o2) * i1;                                  \
                o0 = (f0 - l10 * o1 - l20 * o2) * i0;                       \
            }

            for (int k = 0; k < 3; ++k) {  // P = A^-1 C[t]
                double o0, o1, o2;
                SOLVE3(C[t][k], C[t][3 + k], C[t][6 + k], o0, o1, o2);
                P[t][k] = o0; P[t][3 + k] = o1; P[t][6 + k] = o2;
            }
            if (j + 1 < n) {               // Q = A^-1 C[t+stride]^T
                const int tr = t + stride;
                for (int k = 0; k < 3; ++k) {
                    double o0, o1, o2;
                    SOLVE3(C[tr][3 * k], C[tr][3 * k + 1], C[tr][3 * k + 2], o0, o1, o2);
                    Q[t][k] = o0; Q[t][3 + k] = o1; Q[t][6 + k] = o2;
                }
            }
            {
                double o0, o1, o2;
                SOLVE3(bb[t][0], bb[t][1], bb[t][2], o0, o1, o2);
                z[t][0] = o0; z[t][1] = o1; z[t][2] = o2;
            }
#undef SOLVE3
        }
        __syncthreads();

        // even phase: Schur-update surviving blocks
        j = 2 * tid;
        if (j < n) {
            const int t = j * stride;
            double a00 = A[t][0], a01 = A[t][1], a02 = A[t][2];
            double a11 = A[t][3], a12 = A[t][4], a22 = A[t][5];
            double b0 = bb[t][0], b1 = bb[t][1], b2 = bb[t][2];
            double nc[9];
            const bool hasL = (j > 0);
            if (hasL) {
                const int ti = t - stride;
                double Ct[9];
                for (int k = 0; k < 9; ++k) Ct[k] = C[t][k];
                const double* Qi = Q[ti];
                a00 -= Ct[0] * Qi[0] + Ct[1] * Qi[3] + Ct[2] * Qi[6];
                a01 -= Ct[0] * Qi[1] + Ct[1] * Qi[4] + Ct[2] * Qi[7];
                a02 -= Ct[0] * Qi[2] + Ct[1] * Qi[5] + Ct[2] * Qi[8];
                a11 -= Ct[3] * Qi[1] + Ct[4] * Qi[4] + Ct[5] * Qi[7];
                a12 -= Ct[3] * Qi[2] + Ct[4] * Qi[5] + Ct[5] * Qi[8];
                a22 -= Ct[6] * Qi[2] + Ct[7] * Qi[5] + Ct[8] * Qi[8];
                const double* Pi = P[ti];
                for (int r0 = 0; r0 < 3; ++r0)
                    for (int c0 = 0; c0 < 3; ++c0)
                        nc[3 * r0 + c0] = -(Ct[3 * r0] * Pi[c0] +
                                            Ct[3 * r0 + 1] * Pi[3 + c0] +
                                            Ct[3 * r0 + 2] * Pi[6 + c0]);
                const double* zi = z[ti];
                b0 -= Ct[0] * zi[0] + Ct[1] * zi[1] + Ct[2] * zi[2];
                b1 -= Ct[3] * zi[0] + Ct[4] * zi[1] + Ct[5] * zi[2];
                b2 -= Ct[6] * zi[0] + Ct[7] * zi[1] + Ct[8] * zi[2];
            }
            if (j + 1 < n) {
                const int ti = t + stride;
                double Cr[9];
                for (int k = 0; k < 9; ++k) Cr[k] = C[ti][k];
                const double* Pi = P[ti];
                a00 -= Cr[0] * Pi[0] + Cr[3] * Pi[3] + Cr[6] * Pi[6];
                a01 -= Cr[0] * Pi[1] + Cr[3] * Pi[4] + Cr[6] * Pi[7];
                a02 -= Cr[0] * Pi[2] + Cr[3] * Pi[5] + Cr[6] * Pi[8];
                a11 -= Cr[1] * Pi[1] + Cr[4] * Pi[4] + Cr[7] * Pi[7];
                a12 -= Cr[1] * Pi[2] + Cr[4] * Pi[5] + Cr[7] * Pi[8];
                a22 -= Cr[2] * Pi[2] + Cr[5] * Pi[5] + Cr[8] * Pi[8];
                const double* zi = z[ti];
                b0 -= Cr[0] * zi[0] + Cr[3] * zi[1] + Cr[6] * zi[2];
                b1 -= Cr[1] * zi[0] + Cr[4] * zi[1] + Cr[7] * zi[2];
                b2 -= Cr[2] * zi[0] + Cr[5] * zi[1] + Cr[8] * zi[2];
            }
            A[t][0] = a00; A[t][1] = a01; A[t][2] = a02;
            A[t][3] = a11; A[t][4] = a12; A[t][5] = a22;
            bb[t][0] = b0; bb[t][1] = b1; bb[t][2] = b2;
            if (hasL)
                for (int k = 0; k < 9; ++k) C[t][k] = nc[k];
        }
        __syncthreads();

        n = (n + 1) / 2;
        stride *= 2;
        ++nlev;
    }

    // ---------------- root solve (slot 0) ----------------
    if (tid == 0) {
        const double a00 = A[0][0], a01 = A[0][1], a02 = A[0][2];
        const double a11 = A[0][3], a12 = A[0][4], a22 = A[0][5];
        const double l00 = sqrt(a00), i0 = 1.0 / l00;
        const double l10 = a01 * i0, l20 = a02 * i0;
        const double l11 = sqrt(a11 - l10 * l10), i1 = 1.0 / l11;
        const double l21 = (a12 - l20 * l10) * i1;
        const double l22 = sqrt(a22 - l20 * l20 - l21 * l21), i2 = 1.0 / l22;
        const double f0 = bb[0][0] * i0;
        const double f1 = (bb[0][1] - l10 * f0) * i1;
        const double f2 = (bb[0][2] - l20 * f0 - l21 * f1) * i2;
        const double x2 = f2 * i2;
        const double x1 = (f1 - l21 * x2) * i1;
        const double x0 = (f0 - l10 * x1 - l20 * x2) * i0;
        X[0][0] = x0; X[0][1] = x1; X[0][2] = x2;
    }
    __syncthreads();

    // ---------------- back-substitution ----------------
    for (int lev = nlev - 1; lev >= 0; --lev) {
        stride >>= 1;
        const int nl = ncount[lev];
        const int j = 2 * tid + 1;
        if (j < nl) {
            const int t = j * stride;
            const double* xl = X[t - stride];
            double v0 = z[t][0], v1 = z[t][1], v2 = z[t][2];
            v0 -= P[t][0] * xl[0] + P[t][1] * xl[1] + P[t][2] * xl[2];
            v1 -= P[t][3] * xl[0] + P[t][4] * xl[1] + P[t][5] * xl[2];
            v2 -= P[t][6] * xl[0] + P[t][7] * xl[1] + P[t][8] * xl[2];
            if (j + 1 < nl) {
                const double* xr = X[t + stride];
                v0 -= Q[t][0] * xr[0] + Q[t][1] * xr[1] + Q[t][2] * xr[2];
                v1 -= Q[t][3] * xr[0] + Q[t][4] * xr[1] + Q[t][5] * xr[2];
                v2 -= Q[t][6] * xr[0] + Q[t][7] * xr[1] + Q[t][8] * xr[2];
            }
            X[t][0] = v0; X[t][1] = v1; X[t][2] = v2;
        }
        __syncthreads();
    }

    // ---------------- outputs ----------------
    if (tid < NSTEP) {
        const int t = tid;
        out[            b * NSTEP + t] = (float)X[t][0];  // u0
        out[25600 +     b * NSTEP + t] = (float)X[t][1];  // u1
        out[51200 +     b * NSTEP + t] = (float)X[t][2];  // u2
        if (t < T1)
            out[77056 + b * T1 + t] = sb[t];              // st copy
    }
    if (tid == 0)
        out[76800 + b] = 0.0f;                            // eps
}

extern "C" void kernel_launch(void* const* d_in, const int* in_sizes, int n_in,
                              void* d_out, int out_size, void* d_ws, size_t ws_size,
                              hipStream_t stream) {
    const float* coeffs = (const float*)d_in[0];
    const float* rhs    = (const float*)d_in[1];
    const float* iv_rhs = (const float*)d_in[2];
    const float* steps  = (const float*)d_in[3];
    float* out = (float*)d_out;

    ode_cr_kernel<<<dim3(NPROB), dim3(128), 0, stream>>>(
        coeffs, rhs, iv_rhs, steps, out);
}

// Round 3
// 70.424 us; speedup vs baseline: 3.7487x; 1.0019x over previous
//
#include <hip/hip_runtime.h>

// BS=32, N_IND=8 -> 256 independent problems; N_STEP=100, ORDER=2 (3x3 blocks).
// AtA block-tridiagonal (verified R1). Block cyclic reduction (verified R2).
// R3 changes: one problem per WAVE (blockDim=64 -> barriers are ~free),
// adjugate-based 3x3 inverse (1 fp64 div, no sqrt chain) instead of Cholesky,
// fully unrolled levels (sizes 100,50,25,13,7,4,2 are compile-time).
#define NPROB 256
#define NSTEP 100
#define T1    99

__global__ __launch_bounds__(64) void ode_cr_kernel(
    const float* __restrict__ coeffs,  // [256][100][3]
    const float* __restrict__ rhs,     // [256][100]
    const float* __restrict__ iv_rhs,  // [256][2]
    const float* __restrict__ steps,   // [256][99]
    float* __restrict__ out)           // u0[25600] u1[25600] u2[25600] eps[256] st[25344]
{
    const int b   = blockIdx.x;
    const int tid = threadIdx.x;

    __shared__ double A[NSTEP][6];   // diag block, sym: a00,a01,a02,a11,a12,a22
    __shared__ double C[NSTEP][9];   // sub-diag block: row t -> col t-stride, row-major
    __shared__ double bb[NSTEP][3];  // rhs
    __shared__ double P[NSTEP][9];   // G_t * C_t
    __shared__ double Q[NSTEP][9];   // G_t * C_{t+stride}^T
    __shared__ double z[NSTEP][3];   // G_t * b_t
    __shared__ double X[NSTEP][3];   // solution

    const float* cb = coeffs + b * NSTEP * 3;
    const float* rb = rhs    + b * NSTEP;
    const float* sb = steps  + b * T1;

    // ---------------- build blocks (2 iterations of 64 lanes) ----------------
    for (int t = tid; t < NSTEP; t += 64) {
        const double c0 = (double)cb[t * 3 + 0];
        const double c1 = (double)cb[t * 3 + 1];
        const double c2 = (double)cb[t * 3 + 2];
        const double r  = (double)rb[t];

        double a00 = c0 * c0, a01 = c0 * c1, a02 = c0 * c2;
        double a11 = c1 * c1, a12 = c1 * c2, a22 = c2 * c2;
        double b0 = c0 * r, b1 = c1 * r, b2 = c2 * r;

        if (t == 0) {
            a00 += 1.0; a11 += 1.0;
            b0 += (double)iv_rhs[b * 2 + 0];
            b1 += (double)iv_rhs[b * 2 + 1];
        }
        if (t < T1) {  // U(h_t)
            const double h = (double)sb[t], h2 = h * h;
            a00 += 2.0;
            a01 += h;
            a02 += 0.5 * h2;
            a11 += h2 + 3.0;
            a12 += 0.5 * h2 * h + 1.5 * h;
            a22 += 0.25 * h2 * h2 + 1.25 * h2;
        }
        if (t > 0) {   // V(h_{t-1}) and coupling E(h_{t-1})
            const double hm = (double)sb[t - 1], hm2 = hm * hm;
            a00 += 2.0;
            a01 -= hm;
            a02 += 0.5 * hm2;
            a11 += hm2 + 3.0;
            a12 -= 0.5 * hm2 * hm + 1.5 * hm;
            a22 += 0.25 * hm2 * hm2 + 1.25 * hm2;

            C[t][0] = -2.0;       C[t][1] = -hm;       C[t][2] = -0.5 * hm2;
            C[t][3] =  hm;        C[t][4] = -3.0;      C[t][5] = -1.5 * hm;
            C[t][6] = -0.5 * hm2; C[t][7] =  1.5 * hm; C[t][8] =  0.25 * hm2;
        }
        A[t][0] = a00; A[t][1] = a01; A[t][2] = a02;
        A[t][3] = a11; A[t][4] = a12; A[t][5] = a22;
        bb[t][0] = b0; bb[t][1] = b1; bb[t][2] = b2;
    }
    __syncthreads();

    // level sizes are compile-time: 100,50,25,13,7,4,2 (then 1 = root)
    const int NC[7] = {100, 50, 25, 13, 7, 4, 2};

    // ---------------- down-sweep ----------------
#pragma unroll
    for (int lev = 0; lev < 7; ++lev) {
        const int n = NC[lev];
        const int stride = 1 << lev;

        // odd phase: G = A^-1 via adjugate (1 fp64 div), P/Q/z = G * {...}
        int j = 2 * tid + 1;
        if (j < n) {
            const int t = j * stride;
            const double a00 = A[t][0], a01 = A[t][1], a02 = A[t][2];
            const double a11 = A[t][3], a12 = A[t][4], a22 = A[t][5];
            const double k00 = a11 * a22 - a12 * a12;
            const double k01 = a02 * a12 - a01 * a22;
            const double k02 = a01 * a12 - a02 * a11;
            const double det = a00 * k00 + a01 * k01 + a02 * k02;
            const double id  = 1.0 / det;
            const double g00 = k00 * id;
            const double g01 = k01 * id;
            const double g02 = k02 * id;
            const double g11 = (a00 * a22 - a02 * a02) * id;
            const double g12 = (a02 * a01 - a00 * a12) * id;
            const double g22 = (a00 * a11 - a01 * a01) * id;

            // P = G * C[t]   (C row-major)
#pragma unroll
            for (int k = 0; k < 3; ++k) {
                const double c0k = C[t][k], c1k = C[t][3 + k], c2k = C[t][6 + k];
                P[t][k]     = g00 * c0k + g01 * c1k + g02 * c2k;
                P[t][3 + k] = g01 * c0k + g11 * c1k + g12 * c2k;
                P[t][6 + k] = g02 * c0k + g12 * c1k + g22 * c2k;
            }
            if (j + 1 < n) {  // Q = G * C[t+stride]^T
                const int tr = t + stride;
#pragma unroll
                for (int k = 0; k < 3; ++k) {
                    const double cr0 = C[tr][3 * k], cr1 = C[tr][3 * k + 1], cr2 = C[tr][3 * k + 2];
                    Q[t][k]     = g00 * cr0 + g01 * cr1 + g02 * cr2;
                    Q[t][3 + k] = g01 * cr0 + g11 * cr1 + g12 * cr2;
                    Q[t][6 + k] = g02 * cr0 + g12 * cr1 + g22 * cr2;
                }
            }
            const double b0 = bb[t][0], b1 = bb[t][1], b2 = bb[t][2];
            z[t][0] = g00 * b0 + g01 * b1 + g02 * b2;
            z[t][1] = g01 * b0 + g11 * b1 + g12 * b2;
            z[t][2] = g02 * b0 + g12 * b1 + g22 * b2;
        }
        __syncthreads();

        // even phase: Schur-update survivors
        j = 2 * tid;
        if (j < n) {
            const int t = j * stride;
            double a00 = A[t][0], a01 = A[t][1], a02 = A[t][2];
            double a11 = A[t][3], a12 = A[t][4], a22 = A[t][5];
            double b0 = bb[t][0], b1 = bb[t][1], b2 = bb[t][2];
            double nc[9];
            const bool hasL = (j > 0);
            if (hasL) {
                const int ti = t - stride;
                double Ct[9];
#pragma unroll
                for (int k = 0; k < 9; ++k) Ct[k] = C[t][k];
                const double* Qi = Q[ti];
                a00 -= Ct[0] * Qi[0] + Ct[1] * Qi[3] + Ct[2] * Qi[6];
                a01 -= Ct[0] * Qi[1] + Ct[1] * Qi[4] + Ct[2] * Qi[7];
                a02 -= Ct[0] * Qi[2] + Ct[1] * Qi[5] + Ct[2] * Qi[8];
                a11 -= Ct[3] * Qi[1] + Ct[4] * Qi[4] + Ct[5] * Qi[7];
                a12 -= Ct[3] * Qi[2] + Ct[4] * Qi[5] + Ct[5] * Qi[8];
                a22 -= Ct[6] * Qi[2] + Ct[7] * Qi[5] + Ct[8] * Qi[8];
                const double* Pi = P[ti];
#pragma unroll
                for (int r0 = 0; r0 < 3; ++r0)
#pragma unroll
                    for (int c0 = 0; c0 < 3; ++c0)
                        nc[3 * r0 + c0] = -(Ct[3 * r0] * Pi[c0] +
                                            Ct[3 * r0 + 1] * Pi[3 + c0] +
                                            Ct[3 * r0 + 2] * Pi[6 + c0]);
                const double* zi = z[ti];
                b0 -= Ct[0] * zi[0] + Ct[1] * zi[1] + Ct[2] * zi[2];
                b1 -= Ct[3] * zi[0] + Ct[4] * zi[1] + Ct[5] * zi[2];
                b2 -= Ct[6] * zi[0] + Ct[7] * zi[1] + Ct[8] * zi[2];
            }
            if (j + 1 < n) {
                const int ti = t + stride;
                double Cr[9];
#pragma unroll
                for (int k = 0; k < 9; ++k) Cr[k] = C[ti][k];
                const double* Pi = P[ti];
                a00 -= Cr[0] * Pi[0] + Cr[3] * Pi[3] + Cr[6] * Pi[6];
                a01 -= Cr[0] * Pi[1] + Cr[3] * Pi[4] + Cr[6] * Pi[7];
                a02 -= Cr[0] * Pi[2] + Cr[3] * Pi[5] + Cr[6] * Pi[8];
                a11 -= Cr[1] * Pi[1] + Cr[4] * Pi[4] + Cr[7] * Pi[7];
                a12 -= Cr[1] * Pi[2] + Cr[4] * Pi[5] + Cr[7] * Pi[8];
                a22 -= Cr[2] * Pi[2] + Cr[5] * Pi[5] + Cr[8] * Pi[8];
                const double* zi = z[ti];
                b0 -= Cr[0] * zi[0] + Cr[3] * zi[1] + Cr[6] * zi[2];
                b1 -= Cr[1] * zi[0] + Cr[4] * zi[1] + Cr[7] * zi[2];
                b2 -= Cr[2] * zi[0] + Cr[5] * zi[1] + Cr[8] * zi[2];
            }
            A[t][0] = a00; A[t][1] = a01; A[t][2] = a02;
            A[t][3] = a11; A[t][4] = a12; A[t][5] = a22;
            bb[t][0] = b0; bb[t][1] = b1; bb[t][2] = b2;
            if (hasL)
#pragma unroll
                for (int k = 0; k < 9; ++k) C[t][k] = nc[k];
        }
        __syncthreads();
    }

    // ---------------- root solve: X_0 = A_0^-1 b_0 ----------------
    if (tid == 0) {
        const double a00 = A[0][0], a01 = A[0][1], a02 = A[0][2];
        const double a11 = A[0][3], a12 = A[0][4], a22 = A[0][5];
        const double k00 = a11 * a22 - a12 * a12;
        const double k01 = a02 * a12 - a01 * a22;
        const double k02 = a01 * a12 - a02 * a11;
        const double det = a00 * k00 + a01 * k01 + a02 * k02;
        const double id  = 1.0 / det;
        const double g00 = k00 * id;
        const double g01 = k01 * id;
        const double g02 = k02 * id;
        const double g11 = (a00 * a22 - a02 * a02) * id;
        const double g12 = (a02 * a01 - a00 * a12) * id;
        const double g22 = (a00 * a11 - a01 * a01) * id;
        const double b0 = bb[0][0], b1 = bb[0][1], b2 = bb[0][2];
        X[0][0] = g00 * b0 + g01 * b1 + g02 * b2;
        X[0][1] = g01 * b0 + g11 * b1 + g12 * b2;
        X[0][2] = g02 * b0 + g12 * b1 + g22 * b2;
    }
    __syncthreads();

    // ---------------- up-sweep: x_t = z_t - P_t x_{t-s} - Q_t x_{t+s} ----------------
#pragma unroll
    for (int lev = 6; lev >= 0; --lev) {
        const int n = NC[lev];
        const int stride = 1 << lev;
        const int j = 2 * tid + 1;
        if (j < n) {
            const int t = j * stride;
            const double* xl = X[t - stride];
            double v0 = z[t][0], v1 = z[t][1], v2 = z[t][2];
            v0 -= P[t][0] * xl[0] + P[t][1] * xl[1] + P[t][2] * xl[2];
            v1 -= P[t][3] * xl[0] + P[t][4] * xl[1] + P[t][5] * xl[2];
            v2 -= P[t][6] * xl[0] + P[t][7] * xl[1] + P[t][8] * xl[2];
            if (j + 1 < n) {
                const double* xr = X[t + stride];
                v0 -= Q[t][0] * xr[0] + Q[t][1] * xr[1] + Q[t][2] * xr[2];
                v1 -= Q[t][3] * xr[0] + Q[t][4] * xr[1] + Q[t][5] * xr[2];
                v2 -= Q[t][6] * xr[0] + Q[t][7] * xr[1] + Q[t][8] * xr[2];
            }
            X[t][0] = v0; X[t][1] = v1; X[t][2] = v2;
        }
        __syncthreads();
    }

    // ---------------- outputs ----------------
    for (int t = tid; t < NSTEP; t += 64) {
        out[            b * NSTEP + t] = (float)X[t][0];  // u0
        out[25600 +     b * NSTEP + t] = (float)X[t][1];  // u1
        out[51200 +     b * NSTEP + t] = (float)X[t][2];  // u2
        if (t < T1)
            out[77056 + b * T1 + t] = sb[t];              // st copy
    }
    if (tid == 0)
        out[76800 + b] = 0.0f;                            // eps
}

extern "C" void kernel_launch(void* const* d_in, const int* in_sizes, int n_in,
                              void* d_out, int out_size, void* d_ws, size_t ws_size,
                              hipStream_t stream) {
    const float* coeffs = (const float*)d_in[0];
    const float* rhs    = (const float*)d_in[1];
    const float* iv_rhs = (const float*)d_in[2];
    const float* steps  = (const float*)d_in[3];
    float* out = (float*)d_out;

    ode_cr_kernel<<<dim3(NPROB), dim3(64), 0, stream>>>(
        coeffs, rhs, iv_rhs, steps, out);
}